// Round 1
// 394.586 us; speedup vs baseline: 1.0865x; 1.0865x over previous
//
#include <hip/hip_runtime.h>
#include <stdint.h>

// BinaryDense: out[8192,4096] = x[8192,4096] @ sign(kernel[4096,4096]) + bias[4096]
// R4: port the GEMM to the 256^2 8-phase template (T2+T3+T4+T5). i8 BK=128 is
// byte-isomorphic to bf16 BK=64 ([row][128B] K-tiles, 16B/lane frags).
// Schedule (per iteration = 2 K-tiles, buf0=tile 2i, buf1=tile 2i+1):
//   regions: A-X = wave rows {0-63,128-191}, A-Y = {64-127,192-255},
//            B-P = cols {0-31,64-95,128-159,192-223}, B-Q = complement.
//   phase p computes quadrant (mi-half = p&1 pattern, ni-half) -> free times
//   B-P@p2, A-X@p3, A-Y@p4, B-Q@p4 per tile; stages (1 unit = 16KB = 2 loads):
//   p1:A-Y(2i+1) p2:B-Q(2i+1) p3:B-P(2i+2) p4:A-X(2i+2)
//   p5:A-Y(2i+2) p6:B-Q(2i+2) p7:B-P(2i+3) p8:A-X(2i+3)
//   -> every unit staged >=1 barrier after its region's last read, consumed with
//   lead >=5 phases. Per-phase s_waitcnt vmcnt(6) (3 units in flight) guarantees
//   cross-wave completion: wave Y's vmcnt(6) at phase p-1 covers loads <= p-5 and
//   precedes the shared barrier that precedes wave X's phase-p ds_read.
// LDS swizzle: chunk q (16B) of row r stored at slot q^(r&7); global_load_lds dest
// stays linear, source address carries the inverse permutation (rule 21).

typedef int int4v __attribute__((ext_vector_type(4)));

constexpr int M = 8192, N = 4096, K = 4096;
constexpr int BM = 256, BN = 256, BK = 128;  // i8 elements (= bytes)
constexpr int NT = K / BK;                   // 32 K-tiles
constexpr int NIT = NT / 2;                  // 16 iterations

__device__ __forceinline__ void gload_lds16(const void* g, void* l) {
  __builtin_amdgcn_global_load_lds(
      (const __attribute__((address_space(1))) unsigned int*)g,
      (__attribute__((address_space(3))) unsigned int*)l, 16, 0, 0);
}

// ---- kernel 1: per-row absmax quantize x -> i8; rscale[row] = rowmax/127 ----
__global__ __launch_bounds__(256) void quant_x_kernel(const float* __restrict__ x,
                                                      signed char* __restrict__ xq,
                                                      float* __restrict__ rscale) {
  const int row = blockIdx.x;
  const int t = threadIdx.x;
  const float* xr = x + (size_t)row * K;
  float4 v[4];
  float mx = 0.f;
#pragma unroll
  for (int i = 0; i < 4; ++i) {
    v[i] = *(const float4*)(xr + t * 16 + i * 4);
    mx = fmaxf(mx, fmaxf(fmaxf(fabsf(v[i].x), fabsf(v[i].y)),
                         fmaxf(fabsf(v[i].z), fabsf(v[i].w))));
  }
#pragma unroll
  for (int off = 32; off >= 1; off >>= 1)
    mx = fmaxf(mx, __shfl_xor(mx, off, 64));
  __shared__ float smax[4];
  if ((t & 63) == 0) smax[t >> 6] = mx;
  __syncthreads();
  const float rm = fmaxf(fmaxf(smax[0], smax[1]), fmaxf(smax[2], smax[3]));
  const float s = (rm > 0.f) ? 127.f / rm : 0.f;
  if (t == 0) rscale[row] = (rm > 0.f) ? rm / 127.f : 0.f;
  uint32_t o[4];
#pragma unroll
  for (int i = 0; i < 4; ++i) {
    float f[4] = {v[i].x, v[i].y, v[i].z, v[i].w};
    uint32_t p = 0;
#pragma unroll
    for (int j = 0; j < 4; ++j) {
      int q = (int)rintf(f[j] * s);  // in [-127,127] by construction
      p |= ((uint32_t)(uint8_t)(signed char)q) << (8 * j);
    }
    o[i] = p;
  }
  *(int4v*)(xq + (size_t)row * K + t * 16) = (int4v){(int)o[0], (int)o[1], (int)o[2], (int)o[3]};
}

// ---- kernel 2: Wq[n][k] = sign(w[k][n]) as i8; 64x64 LDS transpose ----
__global__ __launch_bounds__(256) void sign_t_kernel(const float* __restrict__ w,
                                                     signed char* __restrict__ wq) {
  __shared__ __align__(16) signed char tile[64 * 68];  // pad 68 (4-aligned rows)
  const int n0 = blockIdx.x * 64, k0 = blockIdx.y * 64;
  const int t = threadIdx.x;
#pragma unroll
  for (int i = 0; i < 4; ++i) {
    int kl = (t >> 4) + i * 16;  // 0..63
    int nl = (t & 15) * 4;       // 0..60
    float4 v = *(const float4*)(w + (size_t)(k0 + kl) * N + n0 + nl);
    uint32_t p = 0;
    p |= ((uint32_t)(uint8_t)(signed char)((v.x > 0.f) - (v.x < 0.f)));
    p |= ((uint32_t)(uint8_t)(signed char)((v.y > 0.f) - (v.y < 0.f))) << 8;
    p |= ((uint32_t)(uint8_t)(signed char)((v.z > 0.f) - (v.z < 0.f))) << 16;
    p |= ((uint32_t)(uint8_t)(signed char)((v.w > 0.f) - (v.w < 0.f))) << 24;
    *(uint32_t*)(tile + kl * 68 + nl) = p;
  }
  __syncthreads();
  const int nl = t >> 2;          // 0..63
  const int kc = (t & 3) * 16;    // 0,16,32,48
  uint32_t o[4] = {0, 0, 0, 0};
#pragma unroll
  for (int j = 0; j < 16; ++j)
    o[j >> 2] |= ((uint32_t)(uint8_t)tile[(kc + j) * 68 + nl]) << (8 * (j & 3));
  *(int4v*)(wq + (size_t)(n0 + nl) * K + k0 + kc) =
      (int4v){(int)o[0], (int)o[1], (int)o[2], (int)o[3]};
}

// ---- kernel 3: i8 MFMA GEMM, 256^2 8-phase schedule ----
// A = Xq [M][K] i8, B = Wq [N][K] i8, acc int32 (exact), dequant in epilogue.

#define PHASE(BUF, MIH, NIH, LOADB, ...)                                         \
  {                                                                              \
    asm volatile("s_waitcnt vmcnt(6)" ::: "memory");                             \
    int4v a_[4][2];                                                              \
    _Pragma("unroll") for (int mi_ = 0; mi_ < 4; ++mi_) {                        \
      _Pragma("unroll") for (int kk_ = 0; kk_ < 2; ++kk_) {                      \
        const int row_ = wm * 128 + ((MIH)*4 + mi_) * 16 + l16;                  \
        const int c_ = kk_ * 4 + quad;                                           \
        a_[mi_][kk_] = *(const int4v*)(smem + (BUF)*65536 + row_ * 128 +         \
                                       ((c_ ^ (row_ & 7)) * 16));                \
      }                                                                          \
    }                                                                            \
    if (LOADB) {                                                                 \
      _Pragma("unroll") for (int nj_ = 0; nj_ < 2; ++nj_) {                      \
        _Pragma("unroll") for (int kk_ = 0; kk_ < 2; ++kk_) {                    \
          const int row_ = wn * 64 + ((NIH)*2 + nj_) * 16 + l16;                 \
          const int c_ = kk_ * 4 + quad;                                         \
          breg[nj_][kk_] = *(const int4v*)(smem + (BUF)*65536 + 32768 +          \
                                           row_ * 128 + ((c_ ^ (row_ & 7)) * 16)); \
        }                                                                        \
      }                                                                          \
    }                                                                            \
    __VA_ARGS__;                                                                 \
    __builtin_amdgcn_s_barrier();                                                \
    asm volatile("s_waitcnt lgkmcnt(0)" ::: "memory");                           \
    __builtin_amdgcn_s_setprio(1);                                               \
    _Pragma("unroll") for (int mi_ = 0; mi_ < 4; ++mi_) {                        \
      _Pragma("unroll") for (int nj_ = 0; nj_ < 2; ++nj_) {                      \
        _Pragma("unroll") for (int kk_ = 0; kk_ < 2; ++kk_) {                    \
          acc[(MIH)*4 + mi_][(NIH)*2 + nj_] =                                    \
              __builtin_amdgcn_mfma_i32_16x16x64_i8(                             \
                  a_[mi_][kk_], breg[nj_][kk_],                                  \
                  acc[(MIH)*4 + mi_][(NIH)*2 + nj_], 0, 0, 0);                   \
        }                                                                        \
      }                                                                          \
    }                                                                            \
    __builtin_amdgcn_s_setprio(0);                                               \
    __builtin_amdgcn_s_barrier();                                                \
  }

__global__ __launch_bounds__(512, 2) void gemm_bin_kernel(
    const signed char* __restrict__ Xq,
    const signed char* __restrict__ Wq,
    const float* __restrict__ rscale,
    const float* __restrict__ bias,
    float* __restrict__ out) {
  // buf b: A tile at b*65536, B tile at b*65536+32768. [256 rows][128 B] each,
  // chunk q (16B) of row r at slot q^(r&7).
  __shared__ __align__(16) signed char smem[131072];

  const int tid = threadIdx.x;
  const int w = tid >> 6;
  const int lane = tid & 63;
  const int wm = w >> 2;       // 0..1 -> rows wm*128
  const int wn = w & 3;        // 0..3 -> cols wn*64
  const int quad = lane >> 4;  // k-chunk within K=64 frag
  const int l16 = lane & 15;
  const size_t m0 = (size_t)blockIdx.y * BM;
  const size_t n0 = (size_t)blockIdx.x * BN;

  int4v acc[8][4];
#pragma unroll
  for (int i = 0; i < 8; ++i)
#pragma unroll
    for (int j = 0; j < 4; ++j) acc[i][j] = (int4v){0, 0, 0, 0};
  int4v breg[2][2];

  // stage one 16 KB region (1024 chunks, 512 thr x 2 loads). LDS dest is linear
  // per wave (8-row groups never straddle a 32/64-row segment boundary); the
  // swizzle permutes the *global* source chunk.
  auto stageA = [&](int buf, int half, int tile) {  // half: 0=X rows{0-63,128-191}, 1=Y
    signed char* lb = smem + buf * 65536;
#pragma unroll
    for (int it = 0; it < 2; ++it) {
      int pos = it * 512 + tid;
      int rr = pos >> 3, s = pos & 7;
      int row = half * 64 + (rr & 63) + (rr >> 6) * 128;
      int qg = s ^ (row & 7);
      gload_lds16(Xq + (m0 + row) * (size_t)K + (size_t)tile * BK + qg * 16,
                  lb + row * 128 + s * 16);
    }
  };
  auto stageB = [&](int buf, int half, int tile) {  // half: 0=P cols{0-31,64-95,..}, 1=Q
    signed char* lb = smem + buf * 65536 + 32768;
#pragma unroll
    for (int it = 0; it < 2; ++it) {
      int pos = it * 512 + tid;
      int rr = pos >> 3, s = pos & 7;
      int row = half * 32 + (rr & 31) + (rr >> 5) * 64;
      int qg = s ^ (row & 7);
      gload_lds16(Wq + (n0 + row) * (size_t)K + (size_t)tile * BK + qg * 16,
                  lb + row * 128 + s * 16);
    }
  };

  // prologue: tile0 fully + tile1 {B-P, A-X}; issue order matches consumption.
  stageB(0, 0, 0);  // B-P(0)   loads 1-2
  stageA(0, 0, 0);  // A-X(0)   loads 3-4
  stageA(0, 1, 0);  // A-Y(0)   loads 5-6
  stageB(0, 1, 0);  // B-Q(0)   loads 7-8
  stageB(1, 0, 1);  // B-P(1)   loads 9-10
  stageA(1, 0, 1);  // A-X(1)   loads 11-12
  asm volatile("s_waitcnt vmcnt(6)" ::: "memory");  // units 1-3 resident (all waves)
  __builtin_amdgcn_s_barrier();

#pragma unroll 1
  for (int i = 0; i < NIT; ++i) {
    const int t1 = 2 * i + 1, t2 = 2 * i + 2, t3 = 2 * i + 3;
    const bool more = (i + 1 < NIT);
    // tile 2i in buf0
    PHASE(0, 0, 0, true,  { stageA(1, 1, t1); })            // p1: q(miL,niL)
    PHASE(0, 1, 0, false, { stageB(1, 1, t1); })            // p2: q(miH,niL)
    PHASE(0, 0, 1, true,  { if (more) stageB(0, 0, t2); })  // p3: q(miL,niH)
    PHASE(0, 1, 1, false, { if (more) stageA(0, 0, t2); })  // p4: q(miH,niH)
    // tile 2i+1 in buf1
    PHASE(1, 0, 0, true,  { if (more) stageA(0, 1, t2); })  // p5
    PHASE(1, 1, 0, false, { if (more) stageB(0, 1, t2); })  // p6
    PHASE(1, 0, 1, true,  { if (more) stageB(1, 0, t3); })  // p7
    PHASE(1, 1, 1, false, { if (more) stageA(1, 0, t3); })  // p8
  }

  // epilogue: C/D layout col=lane&15, row=quad*4+reg (dtype-independent)
#pragma unroll
  for (int mi = 0; mi < 8; ++mi) {
    const size_t rbase = m0 + wm * 128 + mi * 16 + quad * 4;
    float sc[4];
#pragma unroll
    for (int r = 0; r < 4; ++r) sc[r] = rscale[rbase + r];
#pragma unroll
    for (int ni = 0; ni < 4; ++ni) {
      const size_t col = n0 + wn * 64 + ni * 16 + l16;
      const float bv = bias[col];
#pragma unroll
      for (int r = 0; r < 4; ++r)
        out[(rbase + r) * N + col] = (float)acc[mi][ni][r] * sc[r] + bv;
    }
  }
}

extern "C" void kernel_launch(void* const* d_in, const int* in_sizes, int n_in,
                              void* d_out, int out_size, void* d_ws, size_t ws_size,
                              hipStream_t stream) {
  const float* x = (const float*)d_in[0];
  const float* kern = (const float*)d_in[1];
  const float* bias = (const float*)d_in[2];
  float* out = (float*)d_out;

  signed char* Xq = (signed char*)d_ws;                 // 32 MiB
  signed char* Wq = Xq + (size_t)M * K;                 // 16 MiB
  float* rscale = (float*)(Wq + (size_t)N * K);         // 32 KiB

  quant_x_kernel<<<M, 256, 0, stream>>>(x, Xq, rscale);
  sign_t_kernel<<<dim3(N / 64, K / 64), dim3(256), 0, stream>>>(kern, Wq);
  gemm_bin_kernel<<<dim3(N / BN, M / BM), 512, 0, stream>>>(Xq, Wq, rscale, bias, out);
}

// Round 2
// 378.263 us; speedup vs baseline: 1.1334x; 1.0432x over previous
//
#include <hip/hip_runtime.h>
#include <stdint.h>

// BinaryDense: out[8192,4096] = x[8192,4096] @ sign(kernel[4096,4096]) + bias[4096]
// R5: reads-ahead 8-phase. R4 measured 1537 cyc/phase = LDS(serial) + MFMA(serial):
// reads issued at phase top + lgkm(0) + MFMA never overlap. Restructure:
//   phase p = { [lgkm waits auto] 16 MFMA(p) ; issue ds_reads for p+1 (WAR-reuse
//               a/b, no extra regs) ; issue 1 stage unit ; vmcnt(4) ; barrier }
// Quadrant order per tile: (0,0),(1,0),(1,1),(0,1) -> A-halves live 2 phases,
// B-halves live 2 phases; 64 ds_read_b128/iter/wave (was 80).
// Read-issue schedule (end of phase -> operands for next phase):
//   p1:A1b0  p2:B1b0  p3:A0b0  p4:A0b1+B0b1  p5:A1b1  p6:B1b1  p7:A0b1  p8:A0b0'+B0b0'
// Stage schedule (1 unit = 16KB = 2 global_load_lds per phase):
//   p1:A-X(b1,t1) p2:B-P(b0,t2) p3:A-Y(b0,t2) p4:B-Q(b0,t2)
//   p5:A-X(b0,t2) p6:B-P(b1,t3) p7:A-Y(b1,t3) p8:B-Q(b1,t3)
// Safety (verified per region): stage >= last-read-service + 1 barrier;
// read-issue phase >= stage phase + 3 (vmcnt(4)/phase => stage s complete by
// end s+2, published by that barrier). Tight cases: A-X(b1) staged p1 read
// end-p4 (=p1+3); A-X(b0) staged p5 read end-p8 (=p5+3). Never vmcnt(0) in loop.

typedef int int4v __attribute__((ext_vector_type(4)));

constexpr int M = 8192, N = 4096, K = 4096;
constexpr int BM = 256, BN = 256, BK = 128;  // i8 elements (= bytes)
constexpr int NT = K / BK;                   // 32 K-tiles
constexpr int NIT = NT / 2;                  // 16 iterations

__device__ __forceinline__ void gload_lds16(const void* g, void* l) {
  __builtin_amdgcn_global_load_lds(
      (const __attribute__((address_space(1))) unsigned int*)g,
      (__attribute__((address_space(3))) unsigned int*)l, 16, 0, 0);
}

// ---- kernel 1: fused prep. blocks [0,M): per-row absmax quantize x -> i8.
//      blocks [M, M+N/64*K/64): sign(w)^T 64x64 tiles. Overlaps both BW streams.
__global__ __launch_bounds__(256) void prep_kernel(const float* __restrict__ x,
                                                   signed char* __restrict__ xq,
                                                   float* __restrict__ rscale,
                                                   const float* __restrict__ w,
                                                   signed char* __restrict__ wq) {
  const int t = threadIdx.x;
  if (blockIdx.x < M) {
    const int row = blockIdx.x;
    const float* xr = x + (size_t)row * K;
    float4 v[4];
    float mx = 0.f;
#pragma unroll
    for (int i = 0; i < 4; ++i) {
      v[i] = *(const float4*)(xr + t * 16 + i * 4);
      mx = fmaxf(mx, fmaxf(fmaxf(fabsf(v[i].x), fabsf(v[i].y)),
                           fmaxf(fabsf(v[i].z), fabsf(v[i].w))));
    }
#pragma unroll
    for (int off = 32; off >= 1; off >>= 1)
      mx = fmaxf(mx, __shfl_xor(mx, off, 64));
    __shared__ float smax[4];
    if ((t & 63) == 0) smax[t >> 6] = mx;
    __syncthreads();
    const float rm = fmaxf(fmaxf(smax[0], smax[1]), fmaxf(smax[2], smax[3]));
    const float s = (rm > 0.f) ? 127.f / rm : 0.f;
    if (t == 0) rscale[row] = (rm > 0.f) ? rm / 127.f : 0.f;
    uint32_t o[4];
#pragma unroll
    for (int i = 0; i < 4; ++i) {
      float f[4] = {v[i].x, v[i].y, v[i].z, v[i].w};
      uint32_t p = 0;
#pragma unroll
      for (int j = 0; j < 4; ++j) {
        int q = (int)rintf(f[j] * s);  // in [-127,127] by construction
        p |= ((uint32_t)(uint8_t)(signed char)q) << (8 * j);
      }
      o[i] = p;
    }
    *(int4v*)(xq + (size_t)row * K + t * 16) =
        (int4v){(int)o[0], (int)o[1], (int)o[2], (int)o[3]};
  } else {
    __shared__ __align__(16) signed char tile[64 * 68];  // pad 68
    const int idx = blockIdx.x - M;
    const int n0 = (idx & 63) * 64, k0 = (idx >> 6) * 64;
#pragma unroll
    for (int i = 0; i < 4; ++i) {
      int kl = (t >> 4) + i * 16;  // 0..63
      int nl = (t & 15) * 4;       // 0..60
      float4 v = *(const float4*)(w + (size_t)(k0 + kl) * N + n0 + nl);
      uint32_t p = 0;
      p |= ((uint32_t)(uint8_t)(signed char)((v.x > 0.f) - (v.x < 0.f)));
      p |= ((uint32_t)(uint8_t)(signed char)((v.y > 0.f) - (v.y < 0.f))) << 8;
      p |= ((uint32_t)(uint8_t)(signed char)((v.z > 0.f) - (v.z < 0.f))) << 16;
      p |= ((uint32_t)(uint8_t)(signed char)((v.w > 0.f) - (v.w < 0.f))) << 24;
      *(uint32_t*)(tile + kl * 68 + nl) = p;
    }
    __syncthreads();
    const int nl = t >> 2;        // 0..63
    const int kc = (t & 3) * 16;  // 0,16,32,48
    uint32_t o[4] = {0, 0, 0, 0};
#pragma unroll
    for (int j = 0; j < 16; ++j)
      o[j >> 2] |= ((uint32_t)(uint8_t)tile[(kc + j) * 68 + nl]) << (8 * (j & 3));
    *(int4v*)(wq + (size_t)(n0 + nl) * K + k0 + kc) =
        (int4v){(int)o[0], (int)o[1], (int)o[2], (int)o[3]};
  }
}

// ---- kernel 2: i8 MFMA GEMM, reads-ahead 8-phase schedule ----
// A = Xq [M][K] i8, B = Wq [N][K] i8, acc int32 (exact), dequant in epilogue.
// LDS: buf b at b*65536 (A) / b*65536+32768 (B); chunk q of row r at slot q^(r&7).

#define RD_A(BUF, HALF)                                                       \
  {                                                                           \
    _Pragma("unroll") for (int mi_ = 0; mi_ < 4; ++mi_) {                     \
      _Pragma("unroll") for (int kk_ = 0; kk_ < 2; ++kk_) {                   \
        const int r_ = wm * 128 + (HALF)*64 + mi_ * 16 + l16;                 \
        a[mi_][kk_] = *(const int4v*)(smem + (BUF)*65536 + r_ * 128 +         \
                                      (((kk_ * 4 + quad) ^ (r_ & 7)) * 16));  \
      }                                                                       \
    }                                                                         \
  }

#define RD_B(BUF, HALF)                                                       \
  {                                                                           \
    _Pragma("unroll") for (int nj_ = 0; nj_ < 2; ++nj_) {                     \
      _Pragma("unroll") for (int kk_ = 0; kk_ < 2; ++kk_) {                   \
        const int r_ = wn * 64 + (HALF)*32 + nj_ * 16 + l16;                  \
        b[nj_][kk_] = *(const int4v*)(smem + (BUF)*65536 + 32768 + r_ * 128 + \
                                      (((kk_ * 4 + quad) ^ (r_ & 7)) * 16));  \
      }                                                                       \
    }                                                                         \
  }

// phase: MFMA quadrant (compiler inserts counted lgkm waits for a/b), then
// issue next phase's ds_reads (WAR on a/b), then stage, then counted vmcnt+bar.
#define PH(MIH, NIH, RDBLK, STBLK)                                            \
  {                                                                           \
    __builtin_amdgcn_s_setprio(1);                                            \
    _Pragma("unroll") for (int kk_ = 0; kk_ < 2; ++kk_) {                     \
      _Pragma("unroll") for (int mi_ = 0; mi_ < 4; ++mi_) {                   \
        _Pragma("unroll") for (int nj_ = 0; nj_ < 2; ++nj_) {                 \
          acc[(MIH)*4 + mi_][(NIH)*2 + nj_] =                                 \
              __builtin_amdgcn_mfma_i32_16x16x64_i8(                          \
                  a[mi_][kk_], b[nj_][kk_],                                   \
                  acc[(MIH)*4 + mi_][(NIH)*2 + nj_], 0, 0, 0);                \
        }                                                                     \
      }                                                                       \
    }                                                                         \
    __builtin_amdgcn_s_setprio(0);                                            \
    RDBLK;                                                                    \
    STBLK;                                                                    \
    asm volatile("s_waitcnt vmcnt(4)" ::: "memory");                          \
    __builtin_amdgcn_s_barrier();                                             \
  }

__global__ __launch_bounds__(512, 2) void gemm_bin_kernel(
    const signed char* __restrict__ Xq,
    const signed char* __restrict__ Wq,
    const float* __restrict__ rscale,
    const float* __restrict__ bias,
    float* __restrict__ out) {
  __shared__ __align__(16) signed char smem[131072];

  const int tid = threadIdx.x;
  const int w = tid >> 6;
  const int lane = tid & 63;
  const int wm = w >> 2;       // 0..1 -> rows wm*128
  const int wn = w & 3;        // 0..3 -> cols wn*64
  const int quad = lane >> 4;  // k-chunk within K=64 frag
  const int l16 = lane & 15;
  const size_t m0 = (size_t)blockIdx.y * BM;
  const size_t n0 = (size_t)blockIdx.x * BN;

  int4v acc[8][4];
#pragma unroll
  for (int i = 0; i < 8; ++i)
#pragma unroll
    for (int j = 0; j < 4; ++j) acc[i][j] = (int4v){0, 0, 0, 0};
  int4v a[4][2];  // current A-half fragments (WAR-reused across phases)
  int4v b[2][2];  // current B-half fragments

  // stage one 16 KB region (1024 chunks, 512 thr x 2 loads); LDS dest linear
  // per wave, swizzle applied to the *global* source chunk (rule 21).
  auto stageA = [&](int buf, int half, int tile) {  // half 0: rows{0-63,128-191}
    signed char* lb = smem + buf * 65536;
#pragma unroll
    for (int it = 0; it < 2; ++it) {
      int pos = it * 512 + tid;
      int rr = pos >> 3, s = pos & 7;
      int row = half * 64 + (rr & 63) + (rr >> 6) * 128;
      int qg = s ^ (row & 7);
      gload_lds16(Xq + (m0 + row) * (size_t)K + (size_t)tile * BK + qg * 16,
                  lb + row * 128 + s * 16);
    }
  };
  auto stageB = [&](int buf, int half, int tile) {  // half 0: cols{0-31,64-95,..}
    signed char* lb = smem + buf * 65536 + 32768;
#pragma unroll
    for (int it = 0; it < 2; ++it) {
      int pos = it * 512 + tid;
      int rr = pos >> 3, s = pos & 7;
      int row = half * 32 + (rr & 31) + (rr >> 5) * 64;
      int qg = s ^ (row & 7);
      gload_lds16(Wq + (n0 + row) * (size_t)K + (size_t)tile * BK + qg * 16,
                  lb + row * 128 + s * 16);
    }
  };

  // prologue: buf0 tile0 (4 units) + buf1 tile1 {B-P, A-Y, B-Q} (3 units).
  // A-X(b1,t1) is staged at p1 of iter 0 (steady-state slot).
  stageB(0, 0, 0);  // units 1-2 (loads)
  stageA(0, 0, 0);
  stageA(0, 1, 0);
  stageB(0, 1, 0);  // buf0 complete after first 8 loads
  stageB(1, 0, 1);
  stageA(1, 1, 1);
  stageB(1, 1, 1);
  asm volatile("s_waitcnt vmcnt(6)" ::: "memory");  // oldest 8 loads (buf0) done
  __builtin_amdgcn_s_barrier();
  RD_A(0, 0);  // operands for p1
  RD_B(0, 0);

#pragma unroll 1
  for (int i = 0; i < NIT; ++i) {
    const int t1 = 2 * i + 1, t2 = 2 * i + 2, t3 = 2 * i + 3;
    const bool more = (i + 1 < NIT);
    PH(0, 0, { RD_A(0, 1); }, { stageA(1, 0, t1); })                       // p1
    PH(1, 0, { RD_B(0, 1); }, { if (more) stageB(0, 0, t2); })             // p2
    PH(1, 1, { RD_A(0, 0); }, { if (more) stageA(0, 1, t2); })             // p3
    PH(0, 1, { RD_A(1, 0); RD_B(1, 0); }, { if (more) stageB(0, 1, t2); }) // p4
    PH(0, 0, { RD_A(1, 1); }, { if (more) stageA(0, 0, t2); })             // p5
    PH(1, 0, { RD_B(1, 1); }, { if (more) stageB(1, 0, t3); })             // p6
    PH(1, 1, { RD_A(1, 0); }, { if (more) stageA(1, 1, t3); })             // p7
    PH(0, 1, { RD_A(0, 0); RD_B(0, 0); }, { if (more) stageB(1, 1, t3); }) // p8
  }

  // epilogue: C/D layout col=lane&15, row=quad*4+reg (dtype-independent)
#pragma unroll
  for (int mi = 0; mi < 8; ++mi) {
    const size_t rbase = m0 + wm * 128 + mi * 16 + quad * 4;
    float sc[4];
#pragma unroll
    for (int r = 0; r < 4; ++r) sc[r] = rscale[rbase + r];
#pragma unroll
    for (int ni = 0; ni < 4; ++ni) {
      const size_t col = n0 + wn * 64 + ni * 16 + l16;
      const float bv = bias[col];
#pragma unroll
      for (int r = 0; r < 4; ++r)
        out[(rbase + r) * N + col] = (float)acc[mi][ni][r] * sc[r] + bv;
    }
  }
}

extern "C" void kernel_launch(void* const* d_in, const int* in_sizes, int n_in,
                              void* d_out, int out_size, void* d_ws, size_t ws_size,
                              hipStream_t stream) {
  const float* x = (const float*)d_in[0];
  const float* kern = (const float*)d_in[1];
  const float* bias = (const float*)d_in[2];
  float* out = (float*)d_out;

  signed char* Xq = (signed char*)d_ws;                 // 32 MiB
  signed char* Wq = Xq + (size_t)M * K;                 // 16 MiB
  float* rscale = (float*)(Wq + (size_t)N * K);         // 32 KiB

  prep_kernel<<<M + (N / 64) * (K / 64), 256, 0, stream>>>(x, Xq, rscale, kern, Wq);
  gemm_bin_kernel<<<dim3(N / BN, M / BM), 512, 0, stream>>>(Xq, Wq, rscale, bias, out);
}